// Round 1
// baseline (665.598 us; speedup 1.0000x reference)
//
#include <hip/hip_runtime.h>
#include <stdint.h>

// Problem constants
#define B_    8
#define SNEW  16
#define D_    2048
#define H_    16
#define HD_   128
#define PAST_ 4096
#define LOG2E 1.4426950408889634f
#define SCALE 0.08838834764831845f       // 1/sqrt(128)
#define QSCALE (SCALE * LOG2E)           // fold log2(e) into q so softmax uses exp2

#define NCHUNK 16   // attention sequence chunks (wgs per (b,h))

#define KSTRIDE 136  // ushorts per K/Q row (128 + 8 pad)
#define VSTRIDE 18   // ushorts per transposed-V row (16 keys + 2 pad)

typedef __attribute__((ext_vector_type(8))) short bf16x8;
typedef __attribute__((ext_vector_type(4))) float f32x4;

union BF8 { bf16x8 v; unsigned int u[4]; unsigned short s[8]; };

// Packed fp32->bf16 RNE conversion: 1 instruction for 2 elements (T12 recipe).
__device__ __forceinline__ unsigned int pk2(float a, float b) {
  unsigned int r;
  asm("v_cvt_pk_bf16_f32 %0, %1, %2" : "=v"(r) : "v"(a), "v"(b));
  return r;
}

// ---------------- Kernel 0: convert x (fp32) -> xb (bf16) ----------------
__global__ __launch_bounds__(256) void k_cvt_x(const float* __restrict__ x,
                                               unsigned short* __restrict__ xb) {
  int i = blockIdx.x * 256 + threadIdx.x;  // 32768 threads, 8 elems each
  const float4* xs = (const float4*)x;
  float4 a = xs[i * 2], b = xs[i * 2 + 1];
  uint4 v;
  v.x = pk2(a.x, a.y); v.y = pk2(a.z, a.w);
  v.z = pk2(b.x, b.y); v.w = pk2(b.z, b.w);
  ((uint4*)xb)[i] = v;
}

// ---------------- Kernel 1: fused QKV projection ----------------
// out = x @ W + b for W in {Wq,Wk,Wv}; grid = 6144/16 n-tiles, 4 waves split K.
// q gets pre-scaled by QSCALE (includes log2e). Outputs bf16 [B][H][S][HD].
__global__ __launch_bounds__(256) void k_qkv(
    const unsigned short* __restrict__ xb,
    const float* __restrict__ Wq, const float* __restrict__ bq,
    const float* __restrict__ Wk, const float* __restrict__ bk,
    const float* __restrict__ Wv, const float* __restrict__ bv,
    unsigned short* __restrict__ qb, unsigned short* __restrict__ kbn,
    unsigned short* __restrict__ vbn) {
  __shared__ float red[4][128][16];
  const int n0g = blockIdx.x * 16;
  const int mat = n0g >> 11;           // 0=q 1=k 2=v
  const int n0 = n0g & 2047;
  const float* W    = (mat == 0) ? Wq : ((mat == 1) ? Wk : Wv);
  const float* bias = (mat == 0) ? bq : ((mat == 1) ? bk : bv);
  const int tid = threadIdx.x, w = tid >> 6, lane = tid & 63;
  const int nl = lane & 15, g = lane >> 4;

  f32x4 acc[8];
#pragma unroll
  for (int i = 0; i < 8; i++) acc[i] = (f32x4){0.f, 0.f, 0.f, 0.f};

  const int k0w = w * 512;
  // prefetch kc=0's W rows
  float bw[8];
#pragma unroll
  for (int j = 0; j < 8; j++) bw[j] = W[(size_t)(k0w + g * 8 + j) * 2048 + n0 + nl];

  for (int kc = 0; kc < 16; kc++) {
    const int kbase = k0w + kc * 32 + g * 8;
    float nbw[8];
    if (kc < 15) {  // prefetch next kc's W rows; latency hides under MFMAs below
#pragma unroll
      for (int j = 0; j < 8; j++) nbw[j] = W[(size_t)(kbase + 32 + j) * 2048 + n0 + nl];
    }
    BF8 bf;
#pragma unroll
    for (int j2 = 0; j2 < 4; j2++) bf.u[j2] = pk2(bw[2 * j2], bw[2 * j2 + 1]);
#pragma unroll
    for (int mt = 0; mt < 8; mt++) {
      bf16x8 a = *(const bf16x8*)(xb + (size_t)(mt * 16 + nl) * 2048 + kbase);
      acc[mt] = __builtin_amdgcn_mfma_f32_16x16x32_bf16(a, bf.v, acc[mt], 0, 0, 0);
    }
    if (kc < 15) {
#pragma unroll
      for (int j = 0; j < 8; j++) bw[j] = nbw[j];
    }
  }
#pragma unroll
  for (int mt = 0; mt < 8; mt++) {
    red[w][mt * 16 + g * 4 + 0][nl] = acc[mt][0];
    red[w][mt * 16 + g * 4 + 1][nl] = acc[mt][1];
    red[w][mt * 16 + g * 4 + 2][nl] = acc[mt][2];
    red[w][mt * 16 + g * 4 + 3][nl] = acc[mt][3];
  }
  __syncthreads();
  const int m = tid >> 1;
  const int c0 = (tid & 1) * 8;
  float sv[8];
#pragma unroll
  for (int i = 0; i < 8; i++)
    sv[i] = red[0][m][c0 + i] + red[1][m][c0 + i] + red[2][m][c0 + i] +
            red[3][m][c0 + i] + bias[n0 + c0 + i];
  const int bb = m >> 4, srow = m & 15;
  const int nglob = n0 + c0;
  const int hh = nglob >> 7, dd = nglob & 127;
  size_t ob = (((size_t)(bb * H_ + hh) * SNEW + srow) * HD_ + dd);
  uint4 v;
  if (mat == 0) {
    v.x = pk2(sv[0] * QSCALE, sv[1] * QSCALE); v.y = pk2(sv[2] * QSCALE, sv[3] * QSCALE);
    v.z = pk2(sv[4] * QSCALE, sv[5] * QSCALE); v.w = pk2(sv[6] * QSCALE, sv[7] * QSCALE);
    *(uint4*)(qb + ob) = v;
  } else {
    v.x = pk2(sv[0], sv[1]); v.y = pk2(sv[2], sv[3]);
    v.z = pk2(sv[4], sv[5]); v.w = pk2(sv[6], sv[7]);
    if (mat == 1) *(uint4*)(kbn + ob) = v;
    else          *(uint4*)(vbn + ob) = v;
  }
}

// ---------------- Kernel 2: flash-decoding attention ----------------
// grid (NCHUNK, H, B), 256 threads. Each wave owns chunk/4 keys; online softmax
// (base-2 domain) with S^T = K·Q^T MFMA trick. K row-major in LDS; V stored
// TRANSPOSED (Vt[d][key], swizzled) so the PV B-fragment is 4 dword LDS reads.
// K/V tiles are register-prefetched one iteration ahead to hide HBM latency.
__global__ __launch_bounds__(256, 3) void k_attn(
    const float* __restrict__ kcache, const float* __restrict__ vcache,
    const unsigned short* __restrict__ qb, const unsigned short* __restrict__ kbn,
    const unsigned short* __restrict__ vbn,
    float* __restrict__ pO, float* __restrict__ pml) {
  __shared__ char smem[40960];  // 40 KB -> up to 4 wgs/CU
  unsigned short* Klds = (unsigned short*)smem;            // 4 waves x [16][136]  = 17408 B
  unsigned short* Vlds = (unsigned short*)(smem + 17408);  // 4 waves x [128][18]  = 18432 B
  unsigned short* QP   = (unsigned short*)(smem + 35840);  // Q stage 4352 B, then P 4x[16][40] = 5120 B
  float* cO  = (float*)smem;            // alias (after barrier): [4][16][128]
  float* cml = (float*)(smem + 32768);  // alias: [4][16][2]

  const int chunk = blockIdx.x;
  const int h = blockIdx.y, b = blockIdx.z;
  const int bh = b * H_ + h;
  const int tid = threadIdx.x;
  const int w = tid >> 6, lane = tid & 63;
  const int nl = lane & 15, g = lane >> 4;

  const int CK = PAST_ / NCHUNK;       // 256 keys per chunk
  const int key0 = chunk * CK + w * (CK / 4);
  const int NIT = CK / 4 / 16;         // 4 iterations of 16 keys
  const bool lastw = (chunk == NCHUNK - 1) && (w == 3);
  const int itend = NIT + (lastw ? 1 : 0);

  const float4* kbase = (const float4*)(kcache + ((size_t)bh * PAST_ + key0) * HD_);
  const float4* vbase = (const float4*)(vcache + ((size_t)bh * PAST_ + key0) * HD_);

  // Issue tile 0's loads immediately: latency hides under Q staging + barriers.
  float4 kreg[8], vreg[8];
#pragma unroll
  for (int i = 0; i < 8; i++) kreg[i] = kbase[lane + i * 64];
#pragma unroll
  for (int i = 0; i < 8; i++) vreg[i] = vbase[lane + i * 64];

  {  // stage Q (bf16, pre-scaled by QSCALE)
    uint4 v = ((const uint4*)(qb + (size_t)bh * 2048))[tid];
    int e = tid * 8;
    *(uint4*)(QP + (e >> 7) * KSTRIDE + (e & 127)) = v;
  }
  __syncthreads();
  bf16x8 qfrag[4];
#pragma unroll
  for (int kc4 = 0; kc4 < 4; kc4++)
    qfrag[kc4] = *(const bf16x8*)(QP + nl * KSTRIDE + kc4 * 32 + g * 8);
  __syncthreads();  // all waves done reading Q; safe to overlay P
  for (int i = tid; i < 1280; i += 256) ((unsigned int*)QP)[i] = 0u;  // zero P (cols>=16 stay 0)
  __syncthreads();

  unsigned short* Kw = Klds + w * (16 * KSTRIDE);
  unsigned short* Vw = Vlds + w * (128 * VSTRIDE);
  unsigned short* Pw = QP + w * (16 * 40);

  f32x4 Oacc[8];
#pragma unroll
  for (int i = 0; i < 8; i++) Oacc[i] = (f32x4){0.f, 0.f, 0.f, 0.f};
  float m_run = -1e30f, l_run = 0.f;

  for (int it = 0; it < itend; it++) {
    if (it < NIT) {
      // ---- convert + store tile `it` from regs (K row-major, V transposed) ----
#pragma unroll
      for (int i = 0; i < 8; i++) {
        float4 kv = kreg[i];
        int e = (lane + i * 64) * 4;
        uint2 p; p.x = pk2(kv.x, kv.y); p.y = pk2(kv.z, kv.w);
        *(uint2*)(Kw + (e >> 7) * KSTRIDE + (e & 127)) = p;
      }
#pragma unroll
      for (int i = 0; i < 8; i++) {
        float4 vv = vreg[i];
        int idx = lane + i * 64;
        int r = idx >> 5;            // key row 0..15
        int d0 = (idx & 31) * 4;     // head-dim 0..124
        unsigned int c01 = pk2(vv.x, vv.y);
        unsigned int c23 = pk2(vv.z, vv.w);
        int rs = r ^ (((d0 >> 5) & 1) << 3);  // 8-col slot swizzle: 2-way banks
        Vw[(d0 + 0) * VSTRIDE + rs] = (unsigned short)c01;
        Vw[(d0 + 1) * VSTRIDE + rs] = (unsigned short)(c01 >> 16);
        Vw[(d0 + 2) * VSTRIDE + rs] = (unsigned short)c23;
        Vw[(d0 + 3) * VSTRIDE + rs] = (unsigned short)(c23 >> 16);
      }
      // ---- prefetch tile it+1: latency hides under QK/softmax/PV below ----
      if (it + 1 < NIT) {
        const float4* kn = kbase + (size_t)(it + 1) * 512;
        const float4* vn = vbase + (size_t)(it + 1) * 512;
#pragma unroll
        for (int i = 0; i < 8; i++) kreg[i] = kn[lane + i * 64];
#pragma unroll
        for (int i = 0; i < 8; i++) vreg[i] = vn[lane + i * 64];
      }
    } else {  // stage the 16 new tokens (already bf16; L2-warm from k_qkv)
      const uint4* ks = (const uint4*)(kbn + (size_t)bh * 2048);
      const uint4* vs = (const uint4*)(vbn + (size_t)bh * 2048);
#pragma unroll
      for (int i = 0; i < 4; i++) {
        uint4 v = ks[lane + i * 64];
        int e = (lane + i * 64) * 8;
        *(uint4*)(Kw + (e >> 7) * KSTRIDE + (e & 127)) = v;
      }
#pragma unroll
      for (int i = 0; i < 4; i++) {
        uint4 v2 = vs[lane + i * 64];
        int idx = lane + i * 64;
        int r = idx >> 4;             // key row 0..15
        int d0 = (idx & 15) * 8;      // head-dim 0..120
        int rs = r ^ (((d0 >> 5) & 1) << 3);
        unsigned int uu[4] = {v2.x, v2.y, v2.z, v2.w};
#pragma unroll
        for (int j2 = 0; j2 < 4; j2++) {
          Vw[(d0 + 2 * j2 + 0) * VSTRIDE + rs] = (unsigned short)uu[j2];
          Vw[(d0 + 2 * j2 + 1) * VSTRIDE + rs] = (unsigned short)(uu[j2] >> 16);
        }
      }
    }

    // ---- S^T[key][q] = K · Q^T ----
    f32x4 sacc = (f32x4){0.f, 0.f, 0.f, 0.f};
#pragma unroll
    for (int kc4 = 0; kc4 < 4; kc4++) {
      bf16x8 a = *(const bf16x8*)(Kw + nl * KSTRIDE + kc4 * 32 + g * 8);
      sacc = __builtin_amdgcn_mfma_f32_16x16x32_bf16(a, qfrag[kc4], sacc, 0, 0, 0);
    }
    float s0 = sacc[0], s1 = sacc[1], s2 = sacc[2], s3 = sacc[3];
    if (it == NIT) {  // causal mask among the new tokens
      if (g * 4 + 0 > nl) s0 = -1e30f;
      if (g * 4 + 1 > nl) s1 = -1e30f;
      if (g * 4 + 2 > nl) s2 = -1e30f;
      if (g * 4 + 3 > nl) s3 = -1e30f;
    }
    // ---- online softmax, base-2 domain (scores already scaled by log2e) ----
    float kmax = fmaxf(fmaxf(s0, s1), fmaxf(s2, s3));
    kmax = fmaxf(kmax, __shfl_xor(kmax, 16, 64));
    kmax = fmaxf(kmax, __shfl_xor(kmax, 32, 64));
    float newm = fmaxf(m_run, kmax);
    float p0 = exp2f(s0 - newm), p1 = exp2f(s1 - newm);
    float p2 = exp2f(s2 - newm), p3 = exp2f(s3 - newm);
    float psum = p0 + p1 + p2 + p3;
    psum += __shfl_xor(psum, 16, 64);
    psum += __shfl_xor(psum, 32, 64);
    float alpha = exp2f(m_run - newm);
    l_run = l_run * alpha + psum;
    m_run = newm;
    float ar0 = __shfl(alpha, g * 4 + 0, 64);
    float ar1 = __shfl(alpha, g * 4 + 1, 64);
    float ar2 = __shfl(alpha, g * 4 + 2, 64);
    float ar3 = __shfl(alpha, g * 4 + 3, 64);
#pragma unroll
    for (int nt = 0; nt < 8; nt++) {
      Oacc[nt][0] *= ar0; Oacc[nt][1] *= ar1;
      Oacc[nt][2] *= ar2; Oacc[nt][3] *= ar3;
    }
    // P (C-frag: row=key,col=q) -> LDS as P^T[q][key] -> PV A-frag
    *(unsigned int*)(Pw + nl * 40 + g * 4)     = pk2(p0, p1);
    *(unsigned int*)(Pw + nl * 40 + g * 4 + 2) = pk2(p2, p3);
    bf16x8 pfrag = *(const bf16x8*)(Pw + nl * 40 + g * 8);
    // ---- PV: B-frag = 8 consecutive keys at fixed d, straight from Vt ----
#pragma unroll
    for (int nt = 0; nt < 8; nt++) {
      int row = nt * 16 + nl;
      // keys (g*8 .. g*8+7)&15 = (g&1)*8+jj; column-slot swizzle matches writes
      const unsigned int* vp = (const unsigned int*)(
          Vw + row * VSTRIDE + (((g & 1) << 3) ^ ((nt & 2) << 2)));
      BF8 vb;
      vb.u[0] = vp[0]; vb.u[1] = vp[1]; vb.u[2] = vp[2]; vb.u[3] = vp[3];
      Oacc[nt] = __builtin_amdgcn_mfma_f32_16x16x32_bf16(pfrag, vb.v, Oacc[nt], 0, 0, 0);
    }
  }

  __syncthreads();  // staging done everywhere; safe to alias cO/cml
  float* cOw = cO + w * (16 * 128);
#pragma unroll
  for (int nt = 0; nt < 8; nt++) {
    cOw[(g * 4 + 0) * 128 + nt * 16 + nl] = Oacc[nt][0];
    cOw[(g * 4 + 1) * 128 + nt * 16 + nl] = Oacc[nt][1];
    cOw[(g * 4 + 2) * 128 + nt * 16 + nl] = Oacc[nt][2];
    cOw[(g * 4 + 3) * 128 + nt * 16 + nl] = Oacc[nt][3];
  }
  if (g == 0) { cml[(w * 16 + nl) * 2] = m_run; cml[(w * 16 + nl) * 2 + 1] = l_run; }
  __syncthreads();

  // merge the 4 waves -> one partial per wg (base-2 weights)
  const int q = tid >> 4;
  const int d0 = (tid & 15) * 8;
  float M = -1e30f, mws[4], lws[4];
#pragma unroll
  for (int ww = 0; ww < 4; ww++) {
    mws[ww] = cml[(ww * 16 + q) * 2];
    lws[ww] = cml[(ww * 16 + q) * 2 + 1];
    M = fmaxf(M, mws[ww]);
  }
  float L = 0.f, o[8];
#pragma unroll
  for (int i = 0; i < 8; i++) o[i] = 0.f;
#pragma unroll
  for (int ww = 0; ww < 4; ww++) {
    float Wt = exp2f(mws[ww] - M);
    L += Wt * lws[ww];
    const float* src = cO + ww * 2048 + q * 128 + d0;
#pragma unroll
    for (int i = 0; i < 8; i++) o[i] += Wt * src[i];
  }
  size_t pb = (((size_t)bh * NCHUNK + chunk) * 16 + q) * 128 + d0;
  float4 st0 = {o[0], o[1], o[2], o[3]}, st1 = {o[4], o[5], o[6], o[7]};
  *(float4*)(pO + pb) = st0;
  *(float4*)(pO + pb + 4) = st1;
  if ((tid & 15) == 0) {
    size_t mb = (((size_t)bh * NCHUNK + chunk) * 16 + q) * 2;
    pml[mb] = M; pml[mb + 1] = L;
  }
}

// ---------------- Kernel 3: combine chunk partials -> attn (fp32) ----------------
__global__ __launch_bounds__(256) void k_comb(const float* __restrict__ pO,
                                              const float* __restrict__ pml,
                                              float* __restrict__ attn) {
  const int bh = blockIdx.x, tid = threadIdx.x;
  const int q = tid >> 4, d0 = (tid & 15) * 8;
  float M = -1e30f, mc[NCHUNK], lc[NCHUNK];
#pragma unroll
  for (int c = 0; c < NCHUNK; c++) {
    size_t mb = (((size_t)bh * NCHUNK + c) * 16 + q) * 2;
    mc[c] = pml[mb]; lc[c] = pml[mb + 1];
    M = fmaxf(M, mc[c]);
  }
  float L = 0.f, o[8];
#pragma unroll
  for (int i = 0; i < 8; i++) o[i] = 0.f;
#pragma unroll
  for (int c = 0; c < NCHUNK; c++) {
    float Wt = exp2f(mc[c] - M);
    L += Wt * lc[c];
    const float* src = pO + (((size_t)bh * NCHUNK + c) * 16 + q) * 128 + d0;
#pragma unroll
    for (int i = 0; i < 8; i++) o[i] += Wt * src[i];
  }
  float inv = 1.f / L;
  int b = bh >> 4, h = bh & 15;
  float* dst = attn + ((size_t)(b * SNEW + q)) * D_ + h * HD_ + d0;
  float4 s0 = {o[0] * inv, o[1] * inv, o[2] * inv, o[3] * inv};
  float4 s1 = {o[4] * inv, o[5] * inv, o[6] * inv, o[7] * inv};
  *(float4*)dst = s0;
  *(float4*)(dst + 4) = s1;
}

// ---------------- Kernel 4: output projection out = attn @ Wo + bo (fp32) ----------------
__global__ __launch_bounds__(256) void k_oproj(const float* __restrict__ attn,
                                               const float* __restrict__ Wo,
                                               const float* __restrict__ bo,
                                               float* __restrict__ out) {
  __shared__ float red[4][128][16];
  const int n0 = blockIdx.x * 16;
  const int tid = threadIdx.x, w = tid >> 6, lane = tid & 63;
  const int nl = lane & 15, g = lane >> 4;
  f32x4 acc[8];
#pragma unroll
  for (int i = 0; i < 8; i++) acc[i] = (f32x4){0.f, 0.f, 0.f, 0.f};
  const int k0w = w * 512;
  float bw[8];
#pragma unroll
  for (int j = 0; j < 8; j++) bw[j] = Wo[(size_t)(k0w + g * 8 + j) * 2048 + n0 + nl];
  for (int kc = 0; kc < 16; kc++) {
    const int kbase = k0w + kc * 32 + g * 8;
    float nbw[8];
    if (kc < 15) {
#pragma unroll
      for (int j = 0; j < 8; j++) nbw[j] = Wo[(size_t)(kbase + 32 + j) * 2048 + n0 + nl];
    }
    BF8 bf;
#pragma unroll
    for (int j2 = 0; j2 < 4; j2++) bf.u[j2] = pk2(bw[2 * j2], bw[2 * j2 + 1]);
#pragma unroll
    for (int mt = 0; mt < 8; mt++) {
      const float* ap = attn + (size_t)(mt * 16 + nl) * 2048 + kbase;
      float4 a0 = *(const float4*)ap;
      float4 a1 = *(const float4*)(ap + 4);
      BF8 af;
      af.u[0] = pk2(a0.x, a0.y); af.u[1] = pk2(a0.z, a0.w);
      af.u[2] = pk2(a1.x, a1.y); af.u[3] = pk2(a1.z, a1.w);
      acc[mt] = __builtin_amdgcn_mfma_f32_16x16x32_bf16(af.v, bf.v, acc[mt], 0, 0, 0);
    }
    if (kc < 15) {
#pragma unroll
      for (int j = 0; j < 8; j++) bw[j] = nbw[j];
    }
  }
#pragma unroll
  for (int mt = 0; mt < 8; mt++) {
    red[w][mt * 16 + g * 4 + 0][nl] = acc[mt][0];
    red[w][mt * 16 + g * 4 + 1][nl] = acc[mt][1];
    red[w][mt * 16 + g * 4 + 2][nl] = acc[mt][2];
    red[w][mt * 16 + g * 4 + 3][nl] = acc[mt][3];
  }
  __syncthreads();
  const int m = tid >> 1;
  const int c0 = (tid & 1) * 8;
  float sv[8];
#pragma unroll
  for (int i = 0; i < 8; i++)
    sv[i] = red[0][m][c0 + i] + red[1][m][c0 + i] + red[2][m][c0 + i] +
            red[3][m][c0 + i] + bo[n0 + c0 + i];
  float* dst = out + (size_t)m * 2048 + n0 + c0;
  float4 s0 = {sv[0], sv[1], sv[2], sv[3]}, s1 = {sv[4], sv[5], sv[6], sv[7]};
  *(float4*)dst = s0;
  *(float4*)(dst + 4) = s1;
}

// ---------------- Launch ----------------
extern "C" void kernel_launch(void* const* d_in, const int* in_sizes, int n_in,
                              void* d_out, int out_size, void* d_ws, size_t ws_size,
                              hipStream_t stream) {
  const float* x  = (const float*)d_in[0];
  const float* kc = (const float*)d_in[1];
  const float* vc = (const float*)d_in[2];
  const float* Wq = (const float*)d_in[3];
  const float* bq = (const float*)d_in[4];
  const float* Wk = (const float*)d_in[5];
  const float* bk = (const float*)d_in[6];
  const float* Wv = (const float*)d_in[7];
  const float* bv = (const float*)d_in[8];
  const float* Wo = (const float*)d_in[9];
  const float* bo = (const float*)d_in[10];
  float* out = (float*)d_out;

  char* ws = (char*)d_ws;
  unsigned short* xb   = (unsigned short*)(ws + 0);          // 512 KB
  unsigned short* qb   = (unsigned short*)(ws + 524288);     // 512 KB (pre-scaled, log2e folded)
  unsigned short* kbn  = (unsigned short*)(ws + 1048576);    // 512 KB
  unsigned short* vbn  = (unsigned short*)(ws + 1572864);    // 512 KB
  float*          attn = (float*)(ws + 2097152);             // 1 MB
  float*          pO   = (float*)(ws + 3145728);             // 16 MB
  float*          pml  = (float*)(ws + 19922944);            // 256 KB

  k_cvt_x<<<128, 256, 0, stream>>>(x, xb);
  k_qkv<<<384, 256, 0, stream>>>(xb, Wq, bq, Wk, bk, Wv, bv, qb, kbn, vbn);
  k_attn<<<dim3(NCHUNK, H_, B_), 256, 0, stream>>>(kc, vc, qb, kbn, vbn, pO, pml);
  k_comb<<<B_ * H_, 256, 0, stream>>>(pO, pml, attn);
  k_oproj<<<128, 256, 0, stream>>>(attn, Wo, bo, out);
}

// Round 3
// 652.505 us; speedup vs baseline: 1.0201x; 1.0201x over previous
//
#include <hip/hip_runtime.h>
#include <stdint.h>

// Problem constants
#define B_    8
#define SNEW  16
#define D_    2048
#define H_    16
#define HD_   128
#define PAST_ 4096
#define LOG2E 1.4426950408889634f
#define SCALE 0.08838834764831845f       // 1/sqrt(128)
#define QSCALE (SCALE * LOG2E)           // fold log2(e) into q so softmax uses exp2

#define NCHUNK 16   // attention sequence chunks (wgs per (b,h))

typedef __attribute__((ext_vector_type(8))) short bf16x8;
typedef __attribute__((ext_vector_type(4))) float f32x4;

union BF8 { bf16x8 v; unsigned int u[4]; unsigned short s[8]; };

// Packed fp32->bf16 RNE conversion: 1 instruction for 2 elements.
__device__ __forceinline__ unsigned int pk2(float a, float b) {
  unsigned int r;
  asm("v_cvt_pk_bf16_f32 %0, %1, %2" : "=v"(r) : "v"(a), "v"(b));
  return r;
}

// Async global->LDS DMA, 16B per lane. LDS dest = uniform base + lane*16;
// global src is per-lane (pre-swizzle the source, keep LDS linear).
typedef __attribute__((address_space(1))) const unsigned int* as1cu;
typedef __attribute__((address_space(3))) unsigned int* as3u;
__device__ __forceinline__ void gl_lds16(const void* g, void* l) {
  __builtin_amdgcn_global_load_lds((as1cu)g, (as3u)l, 16, 0, 0);
}

// ---------------- Kernel 0: convert x (fp32) -> xb (bf16) ----------------
__global__ __launch_bounds__(256) void k_cvt_x(const float* __restrict__ x,
                                               unsigned short* __restrict__ xb) {
  int i = blockIdx.x * 256 + threadIdx.x;  // 32768 threads, 8 elems each
  const float4* xs = (const float4*)x;
  float4 a = xs[i * 2], b = xs[i * 2 + 1];
  uint4 v;
  v.x = pk2(a.x, a.y); v.y = pk2(a.z, a.w);
  v.z = pk2(b.x, b.y); v.w = pk2(b.z, b.w);
  ((uint4*)xb)[i] = v;
}

// ---------------- Kernel 1: fused QKV projection ----------------
__global__ __launch_bounds__(256) void k_qkv(
    const unsigned short* __restrict__ xb,
    const float* __restrict__ Wq, const float* __restrict__ bq,
    const float* __restrict__ Wk, const float* __restrict__ bk,
    const float* __restrict__ Wv, const float* __restrict__ bv,
    unsigned short* __restrict__ qb, unsigned short* __restrict__ kbn,
    unsigned short* __restrict__ vbn) {
  __shared__ float red[4][128][16];
  const int n0g = blockIdx.x * 16;
  const int mat = n0g >> 11;           // 0=q 1=k 2=v
  const int n0 = n0g & 2047;
  const float* W    = (mat == 0) ? Wq : ((mat == 1) ? Wk : Wv);
  const float* bias = (mat == 0) ? bq : ((mat == 1) ? bk : bv);
  const int tid = threadIdx.x, w = tid >> 6, lane = tid & 63;
  const int nl = lane & 15, g = lane >> 4;

  f32x4 acc[8];
#pragma unroll
  for (int i = 0; i < 8; i++) acc[i] = (f32x4){0.f, 0.f, 0.f, 0.f};

  const int k0w = w * 512;
  float bw[8];
#pragma unroll
  for (int j = 0; j < 8; j++) bw[j] = W[(size_t)(k0w + g * 8 + j) * 2048 + n0 + nl];

  for (int kc = 0; kc < 16; kc++) {
    const int kbase = k0w + kc * 32 + g * 8;
    float nbw[8];
    if (kc < 15) {
#pragma unroll
      for (int j = 0; j < 8; j++) nbw[j] = W[(size_t)(kbase + 32 + j) * 2048 + n0 + nl];
    }
    BF8 bf;
#pragma unroll
    for (int j2 = 0; j2 < 4; j2++) bf.u[j2] = pk2(bw[2 * j2], bw[2 * j2 + 1]);
#pragma unroll
    for (int mt = 0; mt < 8; mt++) {
      bf16x8 a = *(const bf16x8*)(xb + (size_t)(mt * 16 + nl) * 2048 + kbase);
      acc[mt] = __builtin_amdgcn_mfma_f32_16x16x32_bf16(a, bf.v, acc[mt], 0, 0, 0);
    }
    if (kc < 15) {
#pragma unroll
      for (int j = 0; j < 8; j++) bw[j] = nbw[j];
    }
  }
#pragma unroll
  for (int mt = 0; mt < 8; mt++) {
    red[w][mt * 16 + g * 4 + 0][nl] = acc[mt][0];
    red[w][mt * 16 + g * 4 + 1][nl] = acc[mt][1];
    red[w][mt * 16 + g * 4 + 2][nl] = acc[mt][2];
    red[w][mt * 16 + g * 4 + 3][nl] = acc[mt][3];
  }
  __syncthreads();
  const int m = tid >> 1;
  const int c0 = (tid & 1) * 8;
  float sv[8];
#pragma unroll
  for (int i = 0; i < 8; i++)
    sv[i] = red[0][m][c0 + i] + red[1][m][c0 + i] + red[2][m][c0 + i] +
            red[3][m][c0 + i] + bias[n0 + c0 + i];
  const int bb = m >> 4, srow = m & 15;
  const int nglob = n0 + c0;
  const int hh = nglob >> 7, dd = nglob & 127;
  size_t ob = (((size_t)(bb * H_ + hh) * SNEW + srow) * HD_ + dd);
  uint4 v;
  if (mat == 0) {
    v.x = pk2(sv[0] * QSCALE, sv[1] * QSCALE); v.y = pk2(sv[2] * QSCALE, sv[3] * QSCALE);
    v.z = pk2(sv[4] * QSCALE, sv[5] * QSCALE); v.w = pk2(sv[6] * QSCALE, sv[7] * QSCALE);
    *(uint4*)(qb + ob) = v;
  } else {
    v.x = pk2(sv[0], sv[1]); v.y = pk2(sv[2], sv[3]);
    v.z = pk2(sv[4], sv[5]); v.w = pk2(sv[6], sv[7]);
    if (mat == 1) *(uint4*)(kbn + ob) = v;
    else          *(uint4*)(vbn + ob) = v;
  }
}

// ---------------- Kernel 2: flash-decoding attention ----------------
// grid (NCHUNK, H, B), ONE WAVE (64 threads) per workgroup. Each wave owns a
// full 256-key chunk: 16 tiles of 16 keys, K/V staged fp32 into its own
// double-buffered LDS via global_load_lds DMA (zero VGPR cost, burst-issued,
// counted vmcnt waits -> HBM latency hidden under compute). bf16 conversion
// at fragment-read time with v_cvt_pk_bf16_f32. K source pre-swizzled
// (16B-unit XOR on low-3 row bits) so ds_read_b128 frag reads are near the
// bank floor; V linear (PV column reads are 2-way broadcast = free).
// No barriers anywhere; wave writes its partial directly (k_comb merges).
__global__ __launch_bounds__(64) void k_attn(
    const float* __restrict__ kcache, const float* __restrict__ vcache,
    const unsigned short* __restrict__ qb, const unsigned short* __restrict__ kbn,
    const unsigned short* __restrict__ vbn,
    float* __restrict__ pO, float* __restrict__ pml) {
  // K dbuf 2x8KB @0, V dbuf 2x8KB @16384, P [16][40] ushorts @32768 -> 34048 B
  __shared__ __align__(16) char smem[34048];

  const int chunk = blockIdx.x;
  const int h = blockIdx.y, b = blockIdx.z;
  const int bh = b * H_ + h;
  const int lane = threadIdx.x & 63;
  const int nl = lane & 15, g = lane >> 4;

  unsigned short* Pw = (unsigned short*)(smem + 32768);
  // zero P region (wave-private); cols>=16 stay 0 forever
#pragma unroll
  for (int i = 0; i < 5; i++) ((unsigned int*)Pw)[lane + i * 64] = 0u;

  // Per-lane swizzled K source byte-offsets within a 16x512B tile.
  // DMA instr i writes LDS rows 2i,2i+1; storage 16B-unit s=lane&31 must
  // carry logical unit u = s ^ (row&7)  (involution => read applies same XOR).
  int koff[8];
  {
    int rl = lane >> 5, s5 = lane & 31;
#pragma unroll
    for (int i = 0; i < 8; i++) {
      int r = 2 * i + rl;
      koff[i] = r * 512 + ((s5 ^ (r & 7)) << 4);
    }
  }

  // Q fragments straight from global (bf16, pre-scaled by QSCALE)
  bf16x8 qfrag[4];
#pragma unroll
  for (int kc4 = 0; kc4 < 4; kc4++)
    qfrag[kc4] = *(const bf16x8*)(qb + (size_t)bh * 2048 + nl * 128 + kc4 * 32 + g * 8);
  // Drain Q loads so the DMA vmcnt bookkeeping below is exact.
  asm volatile("s_waitcnt vmcnt(0)" ::: "memory");
  __builtin_amdgcn_sched_barrier(0);

  const char* kt = (const char*)kcache + (size_t)(bh * PAST_ + chunk * 256) * 512;
  const char* vt = (const char*)vcache + (size_t)(bh * PAST_ + chunk * 256) * 512;

  // issue tile 0 into buffer 0 (16 DMAs in flight)
#pragma unroll
  for (int i = 0; i < 8; i++) gl_lds16(kt + koff[i], smem + i * 1024);
#pragma unroll
  for (int i = 0; i < 8; i++) gl_lds16(vt + i * 1024 + lane * 16, smem + 16384 + i * 1024);

  f32x4 Oacc[8];
#pragma unroll
  for (int i = 0; i < 8; i++) Oacc[i] = (f32x4){0.f, 0.f, 0.f, 0.f};
  float m_run = -1e30f, l_run = 0.f;

  for (int t = 0; t < 16; t++) {
    if (t < 15) {  // prefetch tile t+1 into the other buffer, then counted wait
      const char* ktn = kt + (size_t)(t + 1) * 8192;
      const char* vtn = vt + (size_t)(t + 1) * 8192;
      char* kb   = smem + ((t + 1) & 1) * 8192;
      char* vbuf = smem + 16384 + ((t + 1) & 1) * 8192;
#pragma unroll
      for (int i = 0; i < 8; i++) gl_lds16(ktn + koff[i], kb + i * 1024);
#pragma unroll
      for (int i = 0; i < 8; i++) gl_lds16(vtn + i * 1024 + lane * 16, vbuf + i * 1024);
      asm volatile("s_waitcnt vmcnt(16)" ::: "memory");  // tile t's 16 DMAs done
    } else {
      asm volatile("s_waitcnt vmcnt(0)" ::: "memory");   // last tile done
    }
    __builtin_amdgcn_sched_barrier(0);

    const char*  Kb = smem + (t & 1) * 8192;
    const float* Vb = (const float*)(smem + 16384 + (t & 1) * 8192);

    // ---- S^T[key][q] = K · Q^T; K frags read from swizzled fp32 LDS ----
    f32x4 sacc = (f32x4){0.f, 0.f, 0.f, 0.f};
#pragma unroll
    for (int kc4 = 0; kc4 < 4; kc4++) {
      int c0 = kc4 * 8 + g * 2;
      int s0i = ((c0 ^ (nl & 7)) << 4), s1i = (((c0 + 1) ^ (nl & 7)) << 4);
      f32x4 a0 = *(const f32x4*)(Kb + nl * 512 + s0i);
      f32x4 a1 = *(const f32x4*)(Kb + nl * 512 + s1i);
      BF8 af;
      af.u[0] = pk2(a0[0], a0[1]); af.u[1] = pk2(a0[2], a0[3]);
      af.u[2] = pk2(a1[0], a1[1]); af.u[3] = pk2(a1[2], a1[3]);
      sacc = __builtin_amdgcn_mfma_f32_16x16x32_bf16(af.v, qfrag[kc4], sacc, 0, 0, 0);
    }

    // ---- online softmax (base-2), P round-trip, rescale ----
    float s0 = sacc[0], s1 = sacc[1], s2 = sacc[2], s3 = sacc[3];
    float kmax = fmaxf(fmaxf(s0, s1), fmaxf(s2, s3));
    kmax = fmaxf(kmax, __shfl_xor(kmax, 16, 64));
    kmax = fmaxf(kmax, __shfl_xor(kmax, 32, 64));
    float newm = fmaxf(m_run, kmax);
    float p0 = exp2f(s0 - newm), p1 = exp2f(s1 - newm);
    float p2 = exp2f(s2 - newm), p3 = exp2f(s3 - newm);
    float psum = p0 + p1 + p2 + p3;
    psum += __shfl_xor(psum, 16, 64);
    psum += __shfl_xor(psum, 32, 64);
    float alpha = exp2f(m_run - newm);
    l_run = l_run * alpha + psum;
    m_run = newm;
    float ar0 = __shfl(alpha, g * 4 + 0, 64);
    float ar1 = __shfl(alpha, g * 4 + 1, 64);
    float ar2 = __shfl(alpha, g * 4 + 2, 64);
    float ar3 = __shfl(alpha, g * 4 + 3, 64);
#pragma unroll
    for (int nt = 0; nt < 8; nt++) {
      Oacc[nt][0] *= ar0; Oacc[nt][1] *= ar1;
      Oacc[nt][2] *= ar2; Oacc[nt][3] *= ar3;
    }
    *(unsigned int*)(Pw + nl * 40 + g * 4)     = pk2(p0, p1);
    *(unsigned int*)(Pw + nl * 40 + g * 4 + 2) = pk2(p2, p3);
    bf16x8 pfrag = *(const bf16x8*)(Pw + nl * 40 + g * 8);

    // ---- PV: B-frag = V columns from linear fp32 LDS (2-way broadcast) ----
#pragma unroll
    for (int nt = 0; nt < 8; nt++) {
      BF8 vb;
#pragma unroll
      for (int j2 = 0; j2 < 4; j2++) {
        int r0 = (g * 8 + 2 * j2) & 15, r1 = (g * 8 + 2 * j2 + 1) & 15;
        vb.u[j2] = pk2(Vb[r0 * 128 + nt * 16 + nl], Vb[r1 * 128 + nt * 16 + nl]);
      }
      Oacc[nt] = __builtin_amdgcn_mfma_f32_16x16x32_bf16(pfrag, vb.v, Oacc[nt], 0, 0, 0);
    }
  }

  // ---- tail: the 16 new tokens (only the chunk-15 wave of each bh);
  // frags direct from global bf16, causal-masked ----
  if (chunk == NCHUNK - 1) {
    const unsigned short* kb_ = kbn + (size_t)bh * 2048;
    const unsigned short* vb_ = vbn + (size_t)bh * 2048;
    f32x4 sacc = (f32x4){0.f, 0.f, 0.f, 0.f};
#pragma unroll
    for (int kc4 = 0; kc4 < 4; kc4++) {
      bf16x8 a = *(const bf16x8*)(kb_ + nl * 128 + kc4 * 32 + g * 8);
      sacc = __builtin_amdgcn_mfma_f32_16x16x32_bf16(a, qfrag[kc4], sacc, 0, 0, 0);
    }
    float s0 = sacc[0], s1 = sacc[1], s2 = sacc[2], s3 = sacc[3];
    if (g * 4 + 0 > nl) s0 = -1e30f;
    if (g * 4 + 1 > nl) s1 = -1e30f;
    if (g * 4 + 2 > nl) s2 = -1e30f;
    if (g * 4 + 3 > nl) s3 = -1e30f;
    float kmax = fmaxf(fmaxf(s0, s1), fmaxf(s2, s3));
    kmax = fmaxf(kmax, __shfl_xor(kmax, 16, 64));
    kmax = fmaxf(kmax, __shfl_xor(kmax, 32, 64));
    float newm = fmaxf(m_run, kmax);
    float p0 = exp2f(s0 - newm), p1 = exp2f(s1 - newm);
    float p2 = exp2f(s2 - newm), p3 = exp2f(s3 - newm);
    float psum = p0 + p1 + p2 + p3;
    psum += __shfl_xor(psum, 16, 64);
    psum += __shfl_xor(psum, 32, 64);
    float alpha = exp2f(m_run - newm);
    l_run = l_run * alpha + psum;
    m_run = newm;
    float ar0 = __shfl(alpha, g * 4 + 0, 64);
    float ar1 = __shfl(alpha, g * 4 + 1, 64);
    float ar2 = __shfl(alpha, g * 4 + 2, 64);
    float ar3 = __shfl(alpha, g * 4 + 3, 64);
#pragma unroll
    for (int nt = 0; nt < 8; nt++) {
      Oacc[nt][0] *= ar0; Oacc[nt][1] *= ar1;
      Oacc[nt][2] *= ar2; Oacc[nt][3] *= ar3;
    }
    *(unsigned int*)(Pw + nl * 40 + g * 4)     = pk2(p0, p1);
    *(unsigned int*)(Pw + nl * 40 + g * 4 + 2) = pk2(p2, p3);
    bf16x8 pfrag = *(const bf16x8*)(Pw + nl * 40 + g * 8);
#pragma unroll
    for (int nt = 0; nt < 8; nt++) {
      BF8 vb;
#pragma unroll
      for (int j2 = 0; j2 < 4; j2++) {
        int r0 = (g * 8 + 2 * j2) & 15, r1 = (g * 8 + 2 * j2 + 1) & 15;
        unsigned int lo = vb_[r0 * 128 + nt * 16 + nl];
        unsigned int hi = vb_[r1 * 128 + nt * 16 + nl];
        vb.u[j2] = lo | (hi << 16);
      }
      Oacc[nt] = __builtin_amdgcn_mfma_f32_16x16x32_bf16(pfrag, vb.v, Oacc[nt], 0, 0, 0);
    }
  }

  // ---- write this wave's partial: stage O in LDS (reuse K buf 0, private)
  // for coalesced float4 stores ----
  float* cOw = (float*)smem;
#pragma unroll
  for (int nt = 0; nt < 8; nt++) {
    cOw[(g * 4 + 0) * 128 + nt * 16 + nl] = Oacc[nt][0];
    cOw[(g * 4 + 1) * 128 + nt * 16 + nl] = Oacc[nt][1];
    cOw[(g * 4 + 2) * 128 + nt * 16 + nl] = Oacc[nt][2];
    cOw[(g * 4 + 3) * 128 + nt * 16 + nl] = Oacc[nt][3];
  }
  size_t pb = ((size_t)bh * NCHUNK + chunk) * 2048;
#pragma unroll
  for (int rr = 0; rr < 8; rr++) {
    int f = lane + rr * 64;
    float4 v = *(const float4*)(cOw + f * 4);
    *(float4*)(pO + pb + f * 4) = v;
  }
  if (g == 0) {
    size_t mb = (((size_t)bh * NCHUNK + chunk) * 16 + nl) * 2;
    pml[mb] = m_run; pml[mb + 1] = l_run;
  }
}

// ---------------- Kernel 3: combine chunk partials -> attn (fp32) ----------------
__global__ __launch_bounds__(256) void k_comb(const float* __restrict__ pO,
                                              const float* __restrict__ pml,
                                              float* __restrict__ attn) {
  const int bh = blockIdx.x, tid = threadIdx.x;
  const int q = tid >> 4, d0 = (tid & 15) * 8;
  float M = -1e30f, mc[NCHUNK], lc[NCHUNK];
#pragma unroll
  for (int c = 0; c < NCHUNK; c++) {
    size_t mb = (((size_t)bh * NCHUNK + c) * 16 + q) * 2;
    mc[c] = pml[mb]; lc[c] = pml[mb + 1];
    M = fmaxf(M, mc[c]);
  }
  float L = 0.f, o[8];
#pragma unroll
  for (int i = 0; i < 8; i++) o[i] = 0.f;
#pragma unroll
  for (int c = 0; c < NCHUNK; c++) {
    float Wt = exp2f(mc[c] - M);
    L += Wt * lc[c];
    const float* src = pO + (((size_t)bh * NCHUNK + c) * 16 + q) * 128 + d0;
#pragma unroll
    for (int i = 0; i < 8; i++) o[i] += Wt * src[i];
  }
  float inv = 1.f / L;
  int b = bh >> 4, h = bh & 15;
  float* dst = attn + ((size_t)(b * SNEW + q)) * D_ + h * HD_ + d0;
  float4 s0 = {o[0] * inv, o[1] * inv, o[2] * inv, o[3] * inv};
  float4 s1 = {o[4] * inv, o[5] * inv, o[6] * inv, o[7] * inv};
  *(float4*)dst = s0;
  *(float4*)(dst + 4) = s1;
}

// ---------------- Kernel 4: output projection out = attn @ Wo + bo (fp32) ----------------
__global__ __launch_bounds__(256) void k_oproj(const float* __restrict__ attn,
                                               const float* __restrict__ Wo,
                                               const float* __restrict__ bo,
                                               float* __restrict__ out) {
  __shared__ float red[4][128][16];
  const int n0 = blockIdx.x * 16;
  const int tid = threadIdx.x, w = tid >> 6, lane = tid & 63;
  const int nl = lane & 15, g = lane >> 4;
  f32x4 acc[8];
#pragma unroll
  for (int i = 0; i < 8; i++) acc[i] = (f32x4){0.f, 0.f, 0.f, 0.f};
  const int k0w = w * 512;
  float bw[8];
#pragma unroll
  for (int j = 0; j < 8; j++) bw[j] = Wo[(size_t)(k0w + g * 8 + j) * 2048 + n0 + nl];
  for (int kc = 0; kc < 16; kc++) {
    const int kbase = k0w + kc * 32 + g * 8;
    float nbw[8];
    if (kc < 15) {
#pragma unroll
      for (int j = 0; j < 8; j++) nbw[j] = Wo[(size_t)(kbase + 32 + j) * 2048 + n0 + nl];
    }
    BF8 bf;
#pragma unroll
    for (int j2 = 0; j2 < 4; j2++) bf.u[j2] = pk2(bw[2 * j2], bw[2 * j2 + 1]);
#pragma unroll
    for (int mt = 0; mt < 8; mt++) {
      const float* ap = attn + (size_t)(mt * 16 + nl) * 2048 + kbase;
      float4 a0 = *(const float4*)ap;
      float4 a1 = *(const float4*)(ap + 4);
      BF8 af;
      af.u[0] = pk2(a0.x, a0.y); af.u[1] = pk2(a0.z, a0.w);
      af.u[2] = pk2(a1.x, a1.y); af.u[3] = pk2(a1.z, a1.w);
      acc[mt] = __builtin_amdgcn_mfma_f32_16x16x32_bf16(af.v, bf.v, acc[mt], 0, 0, 0);
    }
    if (kc < 15) {
#pragma unroll
      for (int j = 0; j < 8; j++) bw[j] = nbw[j];
    }
  }
#pragma unroll
  for (int mt = 0; mt < 8; mt++) {
    red[w][mt * 16 + g * 4 + 0][nl] = acc[mt][0];
    red[w][mt * 16 + g * 4 + 1][nl] = acc[mt][1];
    red[w][mt * 16 + g * 4 + 2][nl] = acc[mt][2];
    red[w][mt * 16 + g * 4 + 3][nl] = acc[mt][3];
  }
  __syncthreads();
  const int m = tid >> 1;
  const int c0 = (tid & 1) * 8;
  float sv[8];
#pragma unroll
  for (int i = 0; i < 8; i++)
    sv[i] = red[0][m][c0 + i] + red[1][m][c0 + i] + red[2][m][c0 + i] +
            red[3][m][c0 + i] + bo[n0 + c0 + i];
  float* dst = out + (size_t)m * 2048 + n0 + c0;
  float4 s0 = {sv[0], sv[1], sv[2], sv[3]}, s1 = {sv[4], sv[5], sv[6], sv[7]};
  *(float4*)dst = s0;
  *(float4*)(dst + 4) = s1;
}

// ---------------- Launch ----------------
extern "C" void kernel_launch(void* const* d_in, const int* in_sizes, int n_in,
                              void* d_out, int out_size, void* d_ws, size_t ws_size,
                              hipStream_t stream) {
  const float* x  = (const float*)d_in[0];
  const float* kc = (const float*)d_in[1];
  const float* vc = (const float*)d_in[2];
  const float* Wq = (const float*)d_in[3];
  const float* bq = (const float*)d_in[4];
  const float* Wk = (const float*)d_in[5];
  const float* bk = (const float*)d_in[6];
  const float* Wv = (const float*)d_in[7];
  const float* bv = (const float*)d_in[8];
  const float* Wo = (const float*)d_in[9];
  const float* bo = (const float*)d_in[10];
  float* out = (float*)d_out;

  char* ws = (char*)d_ws;
  unsigned short* xb   = (unsigned short*)(ws + 0);          // 512 KB
  unsigned short* qb   = (unsigned short*)(ws + 524288);     // 512 KB (pre-scaled, log2e folded)
  unsigned short* kbn  = (unsigned short*)(ws + 1048576);    // 512 KB
  unsigned short* vbn  = (unsigned short*)(ws + 1572864);    // 512 KB
  float*          attn = (float*)(ws + 2097152);             // 1 MB
  float*          pO   = (float*)(ws + 3145728);             // 16 MB
  float*          pml  = (float*)(ws + 19922944);            // 256 KB

  k_cvt_x<<<128, 256, 0, stream>>>(x, xb);
  k_qkv<<<384, 256, 0, stream>>>(xb, Wq, bq, Wk, bk, Wv, bv, qb, kbn, vbn);
  k_attn<<<dim3(NCHUNK, H_, B_), 64, 0, stream>>>(kc, vc, qb, kbn, vbn, pO, pml);
  k_comb<<<B_ * H_, 256, 0, stream>>>(pO, pml, attn);
  k_oproj<<<128, 256, 0, stream>>>(attn, Wo, bo, out);
}